// Round 9
// baseline (160.035 us; speedup 1.0000x reference)
//
#include <hip/hip_runtime.h>
#include <math.h>

// Problem constants (fixed by setup_inputs)
constexpr int N_ = 8, C_ = 256, F_ = 16, WH_ = 784;
constexpr int CH_STRIDE = F_ * WH_;        // 12544 floats between channels
constexpr int COUT_SZ = N_ * F_ * WH_;     // 100352 floats (c output)
constexpr int QP = 392;                    // positions per block (half row)
constexpr int TILE = 56;                   // positions per LDS tile
constexpr int NT = 7;                      // tiles per block (7*56 = 392)
constexpr int F4PT = TILE / 4;             // 14 float4 per channel per tile
constexpr int LSTR = 60;                   // padded LDS row stride (floats):
                                           //   240 B keeps ds_write_b128 16B-aligned;
                                           //   bank step 60%32=28 -> 2-way max (free)
constexpr int BUF_F = C_ * LSTR;           // 15360 floats per buffer (61.4 KB)
constexpr int SOFF = 256 * C_;             // ws offset of S partials

__device__ inline float wave_reduce_sum(float v) {
#pragma unroll
  for (int o = 32; o > 0; o >>= 1) v += __shfl_down(v, o, 64);
  return v;
}

// ---------------- Kernel 1: fused single-read, reg-staged pipeline ---------
// R8 post-mortem: gload_lds staging delivers only ~5 B/cyc/CU on the 50-KB
// stride pattern regardless of segment size (112 vs 224 B: +3%) or async
// depth -> mechanism A/B vs R0's pass A, which sustained 14.6 B/cyc/CU with
// PLAIN per-lane float4 loads on the same stride. This round: reg-staging
// (global_load_dwordx4 -> named st0..st3 -> late ds_write_b128), T14
// issue-early/write-late so the vmcnt wait lands after the G-phase. Plain
// stores also allow PADDED LDS (LSTR=60, impossible with gload_lds/m104),
// cutting the 4-way bank conflicts in both phases to ~2-way (free).
// R5 spill discipline: named scalars only; launch_bounds(1024,4) = 128 VGPR.
// Max-free online softmax (proven R2-R8): S += sum exp(c), G_c += sum e*l;
// g_out = G/S combined across the two halves by K2.
__global__ __launch_bounds__(1024, 4) void fused_kernel(
    const float* __restrict__ l, const float* __restrict__ g,
    const float* __restrict__ w, float* __restrict__ out,
    float* __restrict__ ws) {
  extern __shared__ float dbuf[];  // 2 * BUF_F floats (122880 B)
  __shared__ float w_s[C_];
  __shared__ float e_s[TILE];
  __shared__ float red_s[16];
  __shared__ float gb_s;

  const int bid = blockIdx.x;
  const int nf = bid >> 1, half = bid & 1;
  const int n = nf >> 4, f = nf & 15;
  const int tid = threadIdx.x;
  const int lane = tid & 63, wv = tid >> 6;

  // ---- stage mapping: float4 idx within tile = c*14 + j ----
  // slot k covers idx = k*1024 + tid; k=0..2 all threads, k=3 tid<512.
  const int c0 = (tid) / F4PT,        j0 = (tid) - c0 * F4PT;
  const int c1 = (1024 + tid) / F4PT, j1 = (1024 + tid) - c1 * F4PT;
  const int c2 = (2048 + tid) / F4PT, j2 = (2048 + tid) - c2 * F4PT;
  const int c3 = (3072 + tid) / F4PT, j3 = (3072 + tid) - c3 * F4PT;
  const int og0 = c0 * CH_STRIDE + (j0 << 2), ol0 = c0 * LSTR + (j0 << 2);
  const int og1 = c1 * CH_STRIDE + (j1 << 2), ol1 = c1 * LSTR + (j1 << 2);
  const int og2 = c2 * CH_STRIDE + (j2 << 2), ol2 = c2 * LSTR + (j2 << 2);
  const int og3 = c3 * CH_STRIDE + (j3 << 2), ol3 = c3 * LSTR + (j3 << 2);
  const bool a3 = (tid < 512);
  const size_t gbase =
      (size_t)n * (C_ * CH_STRIDE) + (size_t)f * WH_ + half * QP;

  float* cur = dbuf;
  float* nxt = dbuf + BUF_F;

  // issue tile 0 loads; they fly under the prologue
  float4 st0, st1, st2, st3;
  {
    const float* lp = l + gbase;
    st0 = *reinterpret_cast<const float4*>(lp + og0);
    st1 = *reinterpret_cast<const float4*>(lp + og1);
    st2 = *reinterpret_cast<const float4*>(lp + og2);
    if (a3) st3 = *reinterpret_cast<const float4*>(lp + og3);
  }

  // ---- prologue: w into LDS, gb = sum_c g[n,c]*w[c] ----
  if (tid < C_) w_s[tid] = w[tid];
  float gv = (tid < C_) ? g[n * C_ + tid] * w[tid] : 0.f;
  gv = wave_reduce_sum(gv);
  if (lane == 0) red_s[wv] = gv;
  // write tile 0 (compiler inserts vmcnt wait before first use of st*)
  *reinterpret_cast<float4*>(&cur[ol0]) = st0;
  *reinterpret_cast<float4*>(&cur[ol1]) = st1;
  *reinterpret_cast<float4*>(&cur[ol2]) = st2;
  if (a3) *reinterpret_cast<float4*>(&cur[ol3]) = st3;
  __syncthreads();  // tile 0 resident, w_s + red_s visible
  if (tid == 0) {
    float s = 0.f;
#pragma unroll
    for (int i = 0; i < 16; ++i) s += red_s[i];
    gb_s = s;
  }
  __syncthreads();
  const float gb = gb_s;

  // phase mappings
  const int p16 = tid >> 4, s16 = tid & 15;  // c-phase: 56 pos x 16 slices
  const int gc = tid >> 2, q = tid & 3;      // G-phase: 256 ch x 4 quarters

  float gacc = 0.f;    // G partial: channel gc, positions q*14..q*14+13
  float s_part = 0.f;  // S partial (s16==0 threads)

  for (int t = 0; t < NT; ++t) {
    // issue tile t+1 loads: in flight across BOTH compute phases
    const bool pf = (t + 1 < NT);
    if (pf) {
      const float* lp = l + gbase + (t + 1) * TILE;
      st0 = *reinterpret_cast<const float4*>(lp + og0);
      st1 = *reinterpret_cast<const float4*>(lp + og1);
      st2 = *reinterpret_cast<const float4*>(lp + og2);
      if (a3) st3 = *reinterpret_cast<const float4*>(lp + og3);
    }

    // ---- c-phase: c_p = sum_c l*w + gb; 16 lanes per position ----
    if (tid < TILE * 16) {  // 896 threads, waves 0..13
      float acc = 0.f;
#pragma unroll
      for (int k = 0; k < 16; ++k) {
        const int c = s16 + (k << 4);
        acc = fmaf(cur[c * LSTR + p16], w_s[c], acc);
      }
      acc += __shfl_down(acc, 8, 64);
      acc += __shfl_down(acc, 4, 64);
      acc += __shfl_down(acc, 2, 64);
      acc += __shfl_down(acc, 1, 64);
      if (s16 == 0) {
        const float cp = acc + gb;
        out[nf * WH_ + half * QP + t * TILE + p16] = cp;
        const float e = __expf(cp);
        e_s[p16] = e;
        s_part += e;
      }
    }
    // e_s dependency is LDS-only: wait lgkm, NOT vmcnt (prefetch loads stay
    // in flight). m201-verified pattern; sched_barrier fences hoisting (#18).
    asm volatile("s_waitcnt lgkmcnt(0)" ::: "memory");
    __builtin_amdgcn_s_barrier();
    __builtin_amdgcn_sched_barrier(0);

    // ---- G-phase: thread (gc,q) accumulates 14 positions of channel gc ----
    {
      const int pb = q * F4PT;
#pragma unroll
      for (int j = 0; j < 14; ++j)
        gacc = fmaf(cur[gc * LSTR + pb + j], e_s[pb + j], gacc);
    }

    // write tile t+1 -> nxt (vmcnt wait lands HERE, after all compute)
    if (pf) {
      *reinterpret_cast<float4*>(&nxt[ol0]) = st0;
      *reinterpret_cast<float4*>(&nxt[ol1]) = st1;
      *reinterpret_cast<float4*>(&nxt[ol2]) = st2;
      if (a3) *reinterpret_cast<float4*>(&nxt[ol3]) = st3;
    }
    __syncthreads();  // nxt resident; all cur/e_s reads done before overwrite

    float* tmp = cur; cur = nxt; nxt = tmp;
  }

  // ---- epilogue: publish partials ----
  gacc += __shfl_down(gacc, 2, 64);
  gacc += __shfl_down(gacc, 1, 64);
  if (q == 0) ws[bid * C_ + gc] = gacc;  // 256 G partials per block

  float sp = wave_reduce_sum(s_part);
  if (lane == 0) red_s[wv] = sp;  // red_s reuse: prologue long done
  __syncthreads();
  if (tid == 0) {
    float ssum = 0.f;
#pragma unroll
    for (int i = 0; i < 16; ++i) ssum += red_s[i];
    ws[SOFF + bid] = ssum;  // S partial
  }
}

// ---------------- Kernel 2: combine half partials -> g_out ----------------
// 32768 outputs = 32 blocks x 1024 threads; one (nf, c) each.
__global__ __launch_bounds__(1024) void combine_kernel(
    float* __restrict__ out, const float* __restrict__ ws) {
  const int tg = blockIdx.x * 1024 + threadIdx.x;
  const int nf = tg >> 8, c = tg & 255;
  const int n = nf >> 4, f = nf & 15;
  const int b0 = nf << 1;
  const float G = ws[(b0 + 0) * C_ + c] + ws[(b0 + 1) * C_ + c];
  const float S = ws[SOFF + b0] + ws[SOFF + b0 + 1];
  out[COUT_SZ + (size_t)(n * C_ + c) * F_ + f] = G / S;
}

extern "C" void kernel_launch(void* const* d_in, const int* in_sizes, int n_in,
                              void* d_out, int out_size, void* d_ws,
                              size_t ws_size, hipStream_t stream) {
  const float* l = (const float*)d_in[0];
  const float* g = (const float*)d_in[1];
  const float* w = (const float*)d_in[2];
  float* out = (float*)d_out;
  float* ws = (float*)d_ws;  // [0,65536): G partials; [65536,65792): S
  fused_kernel<<<dim3(2 * N_ * F_), dim3(1024), 2 * BUF_F * sizeof(float),
                 stream>>>(l, g, w, out, ws);
  combine_kernel<<<dim3(32), dim3(1024), 0, stream>>>(out, ws);
}